// Round 14
// baseline (95.848 us; speedup 1.0000x reference)
//
#include <hip/hip_runtime.h>
#include <hip/hip_bf16.h>

// Problem constants
#define NB    4096          // batch
#define ND    256           // dim
#define NP    2             // positives per anchor
#define TOT   (NB * 3)      // 12288 rows: [a | p0 | p1]
#define NEG_INIT (-4.0f)
#define IMIN_SENT (-1073741824)      // mask sentinel for int dots
#define INV_SCALE (1.0f / 16129.0f)  // 1/(127*127)

// F2 is FRAGMENT-MAJOR i8 (R13 layout): for 16-row group g, K-block kk (64
// i8), the 1024-B block F2[g*4096 + kk*1024 + (quad*16 + r15)*16 + j] holds
// K-byte kk*64 + quad*16 + j of row g*16 + r15. Fragment loads = lane*16
// contiguous b128.
typedef float f32x4 __attribute__((ext_vector_type(4)));
typedef int   i32x4 __attribute__((ext_vector_type(4)));

// ws layout (bytes)
#define WS_F_OFF    0                            // uchar[3 MB] i8 fragment-major
#define WS_POS_OFF  (TOT * 256)                  // float[4096*2] pos distances
#define WS_PART_OFF (WS_POS_OFF + NB * NP * 4)   // float[3][4096][32] partial maxima

// Kernel 1: normalize rows of [a | p0 | p1] -> i8 (x127), fragment-major;
// p-rows also emit the exact fp32 positive distance. One wave per row.
__global__ void norm_pos_kernel(const float* __restrict__ anchor,
                                const float* __restrict__ positive,
                                unsigned char* __restrict__ F2,
                                float* __restrict__ posArr) {
    int wid = threadIdx.x >> 6, lane = threadIdx.x & 63;
    int row = blockIdx.x * 4 + wid;              // grid = 3072
    int group = row >> 4, r15 = row & 15;
    int kk = lane >> 4, quad = (lane >> 2) & 3, jj = (lane & 3) * 4;
    int* dst = (int*)(F2 + (size_t)group * 4096 + kk * 1024 + (quad * 16 + r15) * 16 + jj);

    if (row < NB) {
        const float* src = anchor + (size_t)row * ND;
        float4 x = *(const float4*)(src + lane * 4);
        float ss = x.x * x.x + x.y * x.y + x.z * x.z + x.w * x.w;
        #pragma unroll
        for (int m = 1; m < 64; m <<= 1) ss += __shfl_xor(ss, m, 64);
        float inv = 127.0f / fmaxf(sqrtf(ss), 1e-12f);
        int b0 = (int)rintf(x.x * inv) & 0xff;
        int b1 = (int)rintf(x.y * inv) & 0xff;
        int b2 = (int)rintf(x.z * inv) & 0xff;
        int b3 = (int)rintf(x.w * inv) & 0xff;
        *dst = b0 | (b1 << 8) | (b2 << 16) | (b3 << 24);
    } else {
        int q = row - NB;
        int v = q >> 12;                         // 0 or 1
        int j = q & (NB - 1);
        const float* sp = positive + (size_t)(j * NP + v) * ND;
        const float* sa = anchor + (size_t)j * ND;
        float4 xp = *(const float4*)(sp + lane * 4);
        float4 xa = *(const float4*)(sa + lane * 4);
        float sspv = xp.x * xp.x + xp.y * xp.y + xp.z * xp.z + xp.w * xp.w;
        float ssa  = xa.x * xa.x + xa.y * xa.y + xa.z * xa.z + xa.w * xa.w;
        float dot  = xa.x * xp.x + xa.y * xp.y + xa.z * xp.z + xa.w * xp.w;
        #pragma unroll
        for (int m = 1; m < 64; m <<= 1) {
            sspv += __shfl_xor(sspv, m, 64);
            ssa  += __shfl_xor(ssa, m, 64);
            dot  += __shfl_xor(dot, m, 64);
        }
        float invp = 127.0f / fmaxf(sqrtf(sspv), 1e-12f);
        int b0 = (int)rintf(xp.x * invp) & 0xff;
        int b1 = (int)rintf(xp.y * invp) & 0xff;
        int b2 = (int)rintf(xp.z * invp) & 0xff;
        int b3 = (int)rintf(xp.w * invp) & 0xff;
        *dst = b0 | (b1 << 8) | (b2 << 16) | (b3 << 24);
        if (lane == 0) {
            float inva = 1.0f / fmaxf(sqrtf(ssa), 1e-12f);
            float invpf = invp * (1.0f / 127.0f);
            float dn = dot * inva * invpf;
            float sq = 2.0f - 2.0f * dn;
            posArr[j * NP + v] = sqrtf(fmaxf(sq, 1e-12f));
        }
    }
}

// Kernel 2: fused masked-max Gram, INT8, multi-unit blocks with software-
// pipelined B staging. Each block (512 thr, 8 waves x 32 rows) runs 3 units
// (128-col chunks) for one row-block: A loaded once, B double-buffered in
// 2x32 KB LDS halves, unit u+1's global loads register-prefetched under unit
// u's K-loop -> only unit 0's staging is latency-exposed (3x ramp amortize).
// Grid 512 = 2 blocks/CU, 16 waves/CU.
__global__ __launch_bounds__(512) void gram_max_kernel(
        const unsigned char* __restrict__ F2,
        const int* __restrict__ labels,
        float* __restrict__ partials) {
    __shared__ unsigned char ldsB[2 * 32768];     // 64 KB: 2 unit buffers
    __shared__ int slab[384];                     // labels for 3x128 cols
    int tid = threadIdx.x;
    int wid = tid >> 6, lane = tid & 63;
    int l15 = lane & 15, quad = lane >> 4;

    int id = blockIdx.x;                         // 0..511
    int rbi    = id & 15;                        // row-block 0..15
    int cgroup = id >> 4;                        // 0..31 (3 chunks each)

    int rowBase = rbi * 256 + wid * 32;          // 32 rows per wave

    // ---- A preload (b128): groups rbi*16 + wid*2 + s, reused for 3 units.
    i32x4 af[2][4];
    #pragma unroll
    for (int s = 0; s < 2; ++s) {
        const unsigned char* ab = F2 + (size_t)(rbi * 16 + wid * 2 + s) * 4096 + lane * 16;
        #pragma unroll
        for (int kk = 0; kk < 4; ++kk)
            af[s][kk] = *(const i32x4*)(ab + kk * 1024);
    }
    // Row labels, byte-packed. C row = quad*4 + r.
    unsigned rlp[2];
    #pragma unroll
    for (int s = 0; s < 2; ++s) {
        const int* lb = labels + rowBase + s * 16 + quad * 4;
        rlp[s] = (unsigned)lb[0] | ((unsigned)lb[1] << 8)
               | ((unsigned)lb[2] << 16) | ((unsigned)lb[3] << 24);
    }
    // Column labels for all 3 units (contiguous 384 cols, wraps mod NB).
    if (tid < 384) slab[tid] = labels[(cgroup * 384 + tid) & (NB - 1)];

    // ---- B staging helpers: unit u = chunk cgroup*3+u (32 KB, fragment-
    //      major contiguous). Register-batched: 4 x 16 B per thread.
    float4 bt[4];
    auto gloadU = [&](int u) {
        const float4* s = (const float4*)(F2 + (size_t)(cgroup * 3 + u) * 32768);
        #pragma unroll
        for (int j = 0; j < 4; ++j) bt[j] = s[tid + j * 512];
    };
    auto swriteU = [&](int buf) {
        float4* d = (float4*)(ldsB + buf * 32768);
        #pragma unroll
        for (int j = 0; j < 4; ++j) d[tid + j * 512] = bt[j];
    };

    gloadU(0); swriteU(0);
    gloadU(1);                   // unit-1 loads in flight under unit-0 K-loop
    __syncthreads();

    for (int u = 0; u < 3; ++u) {
        int buf = u & 1;
        int c = cgroup * 3 + u;                  // chunk 0..95
        int part = c >> 5;                       // 0=aa, 1=p0, 2=p1

        int vmax[2][4];
        #pragma unroll
        for (int s = 0; s < 2; ++s)
            #pragma unroll
            for (int r = 0; r < 4; ++r) vmax[s][r] = IMIN_SENT;

        // ---- K-loop: 8 tiles of 16 cols, barrier-free.
        #pragma unroll 2
        for (int ct = 0; ct < 8; ++ct) {
            i32x4 bfr[4];
            #pragma unroll
            for (int kk = 0; kk < 4; ++kk)
                bfr[kk] = *(const i32x4*)&ldsB[buf * 32768 + ct * 4096 + kk * 1024 + lane * 16];

            int lc = slab[u * 128 + ct * 16 + l15];
            unsigned lcq = (unsigned)lc * 0x01010101u;

            i32x4 acc[2];
            #pragma unroll
            for (int s = 0; s < 2; ++s) acc[s] = (i32x4){0, 0, 0, 0};
            #pragma unroll
            for (int kk = 0; kk < 4; ++kk)
                #pragma unroll
                for (int s = 0; s < 2; ++s)
                    acc[s] = __builtin_amdgcn_mfma_i32_16x16x64_i8(af[s][kk], bfr[kk], acc[s], 0, 0, 0);

            #pragma unroll
            for (int s = 0; s < 2; ++s) {
                unsigned x = rlp[s] ^ lcq;     // byte r == 0 iff labels equal
                #pragma unroll
                for (int r = 0; r < 4; ++r) {
                    bool neq = ((x >> (8 * r)) & 0xffu) != 0u;
                    int cand = neq ? acc[s][r] : IMIN_SENT;
                    vmax[s][r] = vmax[s][r] > cand ? vmax[s][r] : cand;
                }
            }
        }

        // Per-unit epilogue: reduce across 16 col-lanes, store partials.
        #pragma unroll
        for (int m = 1; m < 16; m <<= 1)
            #pragma unroll
            for (int s = 0; s < 2; ++s)
                #pragma unroll
                for (int r = 0; r < 4; ++r) {
                    int o = __shfl_xor(vmax[s][r], m, 64);
                    vmax[s][r] = vmax[s][r] > o ? vmax[s][r] : o;
                }
        if (l15 == 0) {
            #pragma unroll
            for (int s = 0; s < 2; ++s)
                #pragma unroll
                for (int r = 0; r < 4; ++r) {
                    int row = rowBase + s * 16 + quad * 4 + r;
                    partials[(size_t)part * NB * 32 + (size_t)row * 32 + (c & 31)]
                        = (float)vmax[s][r] * INV_SCALE;
                }
        }

        // Pipeline: write next unit's B (regs already loaded), issue the
        // one after, single barrier. Other buffer's old data (unit u-1) is
        // dead -- all waves passed the previous barrier.
        if (u < 2) {
            swriteU(buf ^ 1);
            if (u == 0) gloadU(2);
            __syncthreads();
        }
    }
}

// Kernel 3: combine per-part chunk partials -> neg distances -> hinge -> mean.
__global__ void finalize_kernel(const float* __restrict__ partials,
                                const float* __restrict__ posArr,
                                float* __restrict__ out) {
    int row = blockIdx.x * 256 + threadIdx.x;    // grid = 16 -> 4096 rows
    const float* pa = partials + (size_t)row * 32;
    const float* pb = pa + (size_t)NB * 32;
    const float* pc = pb + (size_t)NB * 32;
    float ma = NEG_INIT, m0 = NEG_INIT, m1 = NEG_INIT;
    #pragma unroll
    for (int j = 0; j < 32; ++j) {
        ma = fmaxf(ma, pa[j]);
        m0 = fmaxf(m0, pb[j]);
        m1 = fmaxf(m1, pc[j]);
    }
    float n0 = sqrtf(fmaxf(2.0f - 2.0f * fmaxf(ma, m0), 1e-12f));
    float n1 = sqrtf(fmaxf(2.0f - 2.0f * fmaxf(ma, m1), 1e-12f));
    float l = fmaxf(posArr[row * 2 + 0] - n0 + 1.0f, 0.0f)
            + fmaxf(posArr[row * 2 + 1] - n1 + 1.0f, 0.0f);
    int lane = threadIdx.x & 63, wid = threadIdx.x >> 6;
    #pragma unroll
    for (int m = 1; m < 64; m <<= 1) l += __shfl_xor(l, m, 64);
    __shared__ float wsum[4];
    if (lane == 0) wsum[wid] = l;
    __syncthreads();
    if (threadIdx.x == 0) {
        float s = wsum[0] + wsum[1] + wsum[2] + wsum[3];
        atomicAdd(out, s * (1.0f / (NB * NP)));
    }
}

extern "C" void kernel_launch(void* const* d_in, const int* in_sizes, int n_in,
                              void* d_out, int out_size, void* d_ws, size_t ws_size,
                              hipStream_t stream) {
    const float* anchor   = (const float*)d_in[0];
    const float* positive = (const float*)d_in[1];
    const int*   labels   = (const int*)d_in[2];
    float* out = (float*)d_out;

    unsigned char* F2 = (unsigned char*)((char*)d_ws + WS_F_OFF);
    float* posArr     = (float*)((char*)d_ws + WS_POS_OFF);
    float* partials   = (float*)((char*)d_ws + WS_PART_OFF);

    hipMemsetAsync(d_out, 0, sizeof(float), stream);   // off the critical path
    norm_pos_kernel<<<TOT / 4, 256, 0, stream>>>(anchor, positive, F2, posArr);
    gram_max_kernel<<<512, 512, 0, stream>>>(F2, labels, partials);
    finalize_kernel<<<NB / 256, 256, 0, stream>>>(partials, posArr, out);
}

// Round 15
// 85.726 us; speedup vs baseline: 1.1181x; 1.1181x over previous
//
#include <hip/hip_runtime.h>
#include <hip/hip_bf16.h>

// Problem constants
#define NB    4096          // batch
#define ND    256           // dim
#define NP    2             // positives per anchor
#define TOT   (NB * 3)      // 12288 rows: [a | p0 | p1]
#define NCHUNK 48           // 3 parts x 16 chunks; each chunk within one part
#define COLS_PER_CHUNK 256
#define TILES 16
#define IMIN_SENT (-1073741824)      // mask sentinel; < any dot (|dot| <= 4.13M)
#define INV_SCALE (1.0f / 16129.0f)  // 1/(127*127)

// F2 is FRAGMENT-MAJOR i8 (R13 layout): for 16-row group g, K-block kk (64
// i8), the 1024-B block F2[g*4096 + kk*1024 + (quad*16 + r15)*16 + j] holds
// K-byte kk*64 + quad*16 + j of row g*16 + r15. Fragment loads = lane*16
// contiguous b128.
typedef float f32x4 __attribute__((ext_vector_type(4)));
typedef int   i32x4 __attribute__((ext_vector_type(4)));

// ws layout (bytes)
#define WS_F_OFF    0                             // uchar[3 MB] i8 fragment-major
#define WS_POS_OFF  (TOT * 256)                   // float[4096*2] pos distances
#define WS_NEG_OFF  (WS_POS_OFF + NB * NP * 4)    // int[3][4096] neg-dot maxima

// Kernel 1: normalize rows of [a | p0 | p1] -> i8 (x127), fragment-major;
// p-rows also emit the exact fp32 positive distance. One wave per row.
// Blocks 0..47 additionally initialize negmax to the sentinel (stream-ordered
// before gram, so no reliance on workspace poison).
__global__ void norm_pos_kernel(const float* __restrict__ anchor,
                                const float* __restrict__ positive,
                                unsigned char* __restrict__ F2,
                                float* __restrict__ posArr,
                                int* __restrict__ negmax) {
    if (blockIdx.x < 48) negmax[blockIdx.x * 256 + threadIdx.x] = IMIN_SENT;

    int wid = threadIdx.x >> 6, lane = threadIdx.x & 63;
    int row = blockIdx.x * 4 + wid;              // grid = 3072
    int group = row >> 4, r15 = row & 15;
    int kk = lane >> 4, quad = (lane >> 2) & 3, jj = (lane & 3) * 4;
    int* dst = (int*)(F2 + (size_t)group * 4096 + kk * 1024 + (quad * 16 + r15) * 16 + jj);

    if (row < NB) {
        const float* src = anchor + (size_t)row * ND;
        float4 x = *(const float4*)(src + lane * 4);
        float ss = x.x * x.x + x.y * x.y + x.z * x.z + x.w * x.w;
        #pragma unroll
        for (int m = 1; m < 64; m <<= 1) ss += __shfl_xor(ss, m, 64);
        float inv = 127.0f / fmaxf(sqrtf(ss), 1e-12f);
        int b0 = (int)rintf(x.x * inv) & 0xff;
        int b1 = (int)rintf(x.y * inv) & 0xff;
        int b2 = (int)rintf(x.z * inv) & 0xff;
        int b3 = (int)rintf(x.w * inv) & 0xff;
        *dst = b0 | (b1 << 8) | (b2 << 16) | (b3 << 24);
    } else {
        int q = row - NB;
        int v = q >> 12;                         // 0 or 1
        int j = q & (NB - 1);
        const float* sp = positive + (size_t)(j * NP + v) * ND;
        const float* sa = anchor + (size_t)j * ND;
        float4 xp = *(const float4*)(sp + lane * 4);
        float4 xa = *(const float4*)(sa + lane * 4);
        float sspv = xp.x * xp.x + xp.y * xp.y + xp.z * xp.z + xp.w * xp.w;
        float ssa  = xa.x * xa.x + xa.y * xa.y + xa.z * xa.z + xa.w * xa.w;
        float dot  = xa.x * xp.x + xa.y * xp.y + xa.z * xp.z + xa.w * xp.w;
        #pragma unroll
        for (int m = 1; m < 64; m <<= 1) {
            sspv += __shfl_xor(sspv, m, 64);
            ssa  += __shfl_xor(ssa, m, 64);
            dot  += __shfl_xor(dot, m, 64);
        }
        float invp = 127.0f / fmaxf(sqrtf(sspv), 1e-12f);
        int b0 = (int)rintf(xp.x * invp) & 0xff;
        int b1 = (int)rintf(xp.y * invp) & 0xff;
        int b2 = (int)rintf(xp.z * invp) & 0xff;
        int b3 = (int)rintf(xp.w * invp) & 0xff;
        *dst = b0 | (b1 << 8) | (b2 << 16) | (b3 << 24);
        if (lane == 0) {
            float inva = 1.0f / fmaxf(sqrtf(ssa), 1e-12f);
            float invpf = invp * (1.0f / 127.0f);
            float dn = dot * inva * invpf;
            float sq = 2.0f - 2.0f * dn;
            posArr[j * NP + v] = sqrtf(fmaxf(sq, 1e-12f));
        }
    }
}

// Kernel 2: fused masked-max Gram, INT8, R13 structure verbatim (the
// empirical optimum: 768 blocks x 512 thr, fragment-major, one barrier,
// barrier-free K-loop). Epilogue now feeds a device-scope atomicMax into
// negmax[part][row] -- int dots are order-exact, so this replaces the
// 786 KB partials round-trip.
__global__ __launch_bounds__(512) void gram_max_kernel(
        const unsigned char* __restrict__ F2,
        const int* __restrict__ labels,
        int* __restrict__ negmax) {
    __shared__ unsigned char ldsB[TILES * 4096];  // 64 KB
    __shared__ int slab[COLS_PER_CHUNK];          // 1 KB column labels
    int tid = threadIdx.x;
    int wid = tid >> 6, lane = tid & 63;
    int l15 = lane & 15, quad = lane >> 4;

    int id = blockIdx.x;                         // 0..767
    int chunk = id >> 4;                         // 0..47
    int rbi   = id & 15;                         // 0..15 row-block index

    int rowBase = rbi * 256 + wid * 32;          // 32 rows per wave
    int col0 = chunk * COLS_PER_CHUNK;
    int part = chunk >> 4;                       // 0=aa, 1=p0, 2=p1

    // ---- A preload (b128, 1 KB/wave-load): groups rbi*16 + wid*2 + s.
    i32x4 af[2][4];
    #pragma unroll
    for (int s = 0; s < 2; ++s) {
        const unsigned char* ab = F2 + (size_t)(rbi * 16 + wid * 2 + s) * 4096 + lane * 16;
        #pragma unroll
        for (int kk = 0; kk < 4; ++kk)
            af[s][kk] = *(const i32x4*)(ab + kk * 1024);
    }
    // Row labels, byte-packed (labels < 200 fit a byte). C row = quad*4+r.
    unsigned rlp[2];
    #pragma unroll
    for (int s = 0; s < 2; ++s) {
        const int* lb = labels + rowBase + s * 16 + quad * 4;
        rlp[s] = (unsigned)lb[0] | ((unsigned)lb[1] << 8)
               | ((unsigned)lb[2] << 16) | ((unsigned)lb[3] << 24);
    }
    if (tid < COLS_PER_CHUNK) slab[tid] = labels[(col0 & (NB - 1)) + tid];

    // ---- B staging: flat 64 KB copy, already in fragment layout.
    {
        const float4* src = (const float4*)(F2 + (size_t)chunk * 16 * 4096);
        float4* dst = (float4*)ldsB;
        #pragma unroll
        for (int j = 0; j < 8; ++j)
            dst[tid + j * 512] = src[tid + j * 512];
    }

    int vmax[2][4];
    #pragma unroll
    for (int s = 0; s < 2; ++s)
        #pragma unroll
        for (int r = 0; r < 4; ++r) vmax[s][r] = IMIN_SENT;

    __syncthreads();   // the ONLY barrier

    // ---- Barrier-free K-loop: 4 b128 ds_reads + 8 MFMA + mask-fold per tile.
    #pragma unroll 2
    for (int ct = 0; ct < TILES; ++ct) {
        i32x4 bfr[4];
        #pragma unroll
        for (int kk = 0; kk < 4; ++kk)
            bfr[kk] = *(const i32x4*)&ldsB[ct * 4096 + kk * 1024 + lane * 16];

        int lc = slab[ct * 16 + l15];
        unsigned lcq = (unsigned)lc * 0x01010101u;

        i32x4 acc[2];
        #pragma unroll
        for (int s = 0; s < 2; ++s) acc[s] = (i32x4){0, 0, 0, 0};
        #pragma unroll
        for (int kk = 0; kk < 4; ++kk)
            #pragma unroll
            for (int s = 0; s < 2; ++s)
                acc[s] = __builtin_amdgcn_mfma_i32_16x16x64_i8(af[s][kk], bfr[kk], acc[s], 0, 0, 0);

        #pragma unroll
        for (int s = 0; s < 2; ++s) {
            unsigned x = rlp[s] ^ lcq;         // byte r == 0 iff labels equal
            #pragma unroll
            for (int r = 0; r < 4; ++r) {
                bool neq = ((x >> (8 * r)) & 0xffu) != 0u;
                int cand = neq ? acc[s][r] : IMIN_SENT;
                vmax[s][r] = vmax[s][r] > cand ? vmax[s][r] : cand;
            }
        }
    }

    // Reduce max across the 16 column-lanes (same quad = same rows)
    #pragma unroll
    for (int m = 1; m < 16; m <<= 1)
        #pragma unroll
        for (int s = 0; s < 2; ++s)
            #pragma unroll
            for (int r = 0; r < 4; ++r) {
                int o = __shfl_xor(vmax[s][r], m, 64);
                vmax[s][r] = vmax[s][r] > o ? vmax[s][r] : o;
            }

    if (l15 == 0) {
        #pragma unroll
        for (int s = 0; s < 2; ++s)
            #pragma unroll
            for (int r = 0; r < 4; ++r) {
                int row = rowBase + s * 16 + quad * 4 + r;
                atomicMax(&negmax[part * NB + row], vmax[s][r]);
            }
    }
}

// Kernel 3: negmax ints -> neg distances -> hinge -> mean. Reads only 48 KB.
__global__ void finalize_kernel(const int* __restrict__ negmax,
                                const float* __restrict__ posArr,
                                float* __restrict__ out) {
    int row = blockIdx.x * 256 + threadIdx.x;    // grid = 16 -> 4096 rows
    int ia = negmax[row];
    int i0 = negmax[NB + row];
    int i1 = negmax[2 * NB + row];
    int m0 = ia > i0 ? ia : i0;
    int m1 = ia > i1 ? ia : i1;
    // Sentinel path: if a row had all columns masked, value stays IMIN_SENT
    // -> huge neg distance -> hinge clamps to 0, matching the inf reference.
    float d0 = (float)m0 * INV_SCALE;
    float d1 = (float)m1 * INV_SCALE;
    float n0 = sqrtf(fmaxf(2.0f - 2.0f * d0, 1e-12f));
    float n1 = sqrtf(fmaxf(2.0f - 2.0f * d1, 1e-12f));
    float l = fmaxf(posArr[row * 2 + 0] - n0 + 1.0f, 0.0f)
            + fmaxf(posArr[row * 2 + 1] - n1 + 1.0f, 0.0f);
    int lane = threadIdx.x & 63, wid = threadIdx.x >> 6;
    #pragma unroll
    for (int m = 1; m < 64; m <<= 1) l += __shfl_xor(l, m, 64);
    __shared__ float wsum[4];
    if (lane == 0) wsum[wid] = l;
    __syncthreads();
    if (threadIdx.x == 0) {
        float s = wsum[0] + wsum[1] + wsum[2] + wsum[3];
        atomicAdd(out, s * (1.0f / (NB * NP)));
    }
}

extern "C" void kernel_launch(void* const* d_in, const int* in_sizes, int n_in,
                              void* d_out, int out_size, void* d_ws, size_t ws_size,
                              hipStream_t stream) {
    const float* anchor   = (const float*)d_in[0];
    const float* positive = (const float*)d_in[1];
    const int*   labels   = (const int*)d_in[2];
    float* out = (float*)d_out;

    unsigned char* F2 = (unsigned char*)((char*)d_ws + WS_F_OFF);
    float* posArr     = (float*)((char*)d_ws + WS_POS_OFF);
    int*   negmax     = (int*)((char*)d_ws + WS_NEG_OFF);

    hipMemsetAsync(d_out, 0, sizeof(float), stream);   // off the critical path
    norm_pos_kernel<<<TOT / 4, 256, 0, stream>>>(anchor, positive, F2, posArr, negmax);
    gram_max_kernel<<<(NB / 256) * NCHUNK, 512, 0, stream>>>(F2, labels, negmax);
    finalize_kernel<<<NB / 256, 256, 0, stream>>>(negmax, posArr, out);
}